// Round 1
// baseline (1119.877 us; speedup 1.0000x reference)
//
#include <hip/hip_runtime.h>
#include <stdint.h>

#define N_PIX 401408
#define HWIMG 12544   // 112*112
#define LN_EPS 1e-5f

// ---------------- workspace layout ----------------
struct Ws {
  double R[3][8];          // sinkhorn row sums per iter, [iter][c*2+m]
  unsigned cnt4[4];        // class pixel counts (Bn)
  unsigned nmk[8];         // correct counts per (c,m)
  unsigned nCorr;          // size of corrList
  unsigned pad[3];
  float  protoN[8][256];   // l2-normalized prototypes, row r = c*2+m
  float  fAcc[8][256];     // f accumulator
  float2 E2[N_PIX];        // exp(sim/eps) for label class, (m=0, m=1)
  int    corrList[N_PIX];  // compacted indices of correct pixels
};

// ---------------- reductions ----------------
__device__ __forceinline__ float wredf(float v) {   // full 64-lane
#pragma unroll
  for (int o = 32; o > 0; o >>= 1) v += __shfl_xor(v, o, 64);
  return v;
}
__device__ __forceinline__ float wred16(float v) {  // within 16-lane group
  v += __shfl_xor(v, 1, 64);
  v += __shfl_xor(v, 2, 64);
  v += __shfl_xor(v, 4, 64);
  v += __shfl_xor(v, 8, 64);
  return v;
}
__device__ __forceinline__ double wredd(double v) {
#pragma unroll
  for (int o = 32; o > 0; o >>= 1) v += __shfl_xor(v, o, 64);
  return v;
}

// ---------------- K0: zero accumulators ----------------
__global__ __launch_bounds__(256) void k_zero(Ws* __restrict__ ws) {
  int tid = threadIdx.x;
  if (tid < 24) ((double*)ws->R)[tid] = 0.0;
  else if (tid < 32) ws->nmk[tid - 24] = 0u;
  else if (tid < 36) ws->cnt4[tid - 32] = 0u;
  else if (tid == 36) ws->nCorr = 0u;
  for (int i = tid; i < 2048; i += 256) (&ws->fAcc[0][0])[i] = 0.f;
}

// ---------------- K1: per-pixel main ----------------
// 16 lanes per pixel, 4 pixels per wave, 16 pixels per block.
// Lane s owns dims {64L + 4s .. 4s+3, L=0..3}: every global load instruction
// is 256 B contiguous per pixel (vs stride-64 scatter before).
// LDS proto layout: float4 for (row r, chunk l=L*16+s) at word l*32 + 4*(r^(s&7))
// -> reads are conflict-free (2-way s/s+8 alias only, which is free).
__global__ __launch_bounds__(256) void k_main(
    const float* __restrict__ X, const int* __restrict__ label,
    const float* __restrict__ protos,
    const float* __restrict__ fng, const float* __restrict__ fnb,
    const float* __restrict__ mng, const float* __restrict__ mnb,
    Ws* __restrict__ ws,
    float* __restrict__ out_nearest, float* __restrict__ out_logits) {
  __shared__ float prS[2048];
  __shared__ float sR4[4][8];
  __shared__ unsigned sC4[4][4];
  __shared__ unsigned sCorr, sBase;
  __shared__ int sList[16];
  int tid = threadIdx.x;
  int wave = tid >> 6, lane = tid & 63;
  if (tid == 0) sCorr = 0u;

  // normalize prototypes into swizzled LDS (each wave does rows w, w+4)
#pragma unroll
  for (int t = 0; t < 2; t++) {
    int r = wave + t * 4;
    const float4 p = *(const float4*)(protos + r * 256 + lane * 4);
    float ss = p.x * p.x + p.y * p.y + p.z * p.z + p.w * p.w;
    ss = wredf(ss);
    float inv = 1.0f / fmaxf(sqrtf(ss), 1e-12f);
    float4 o; o.x = p.x * inv; o.y = p.y * inv; o.z = p.z * inv; o.w = p.w * inv;
    *(float4*)(&prS[lane * 32 + 4 * (r ^ (lane & 7))]) = o;
    if (blockIdx.x == 0) *(float4*)(&ws->protoN[r][lane * 4]) = o;
  }
  __syncthreads();

  int grp = lane >> 4, s = lane & 15;
  int n = blockIdx.x * 16 + wave * 4 + grp;

  const float* xb = X + (size_t)n * 256 + s * 4;
  const float4 x0 = *(const float4*)(xb);         // dims 4s..4s+3
  const float4 x1 = *(const float4*)(xb + 64);    // dims 64+4s..
  const float4 x2 = *(const float4*)(xb + 128);
  const float4 x3 = *(const float4*)(xb + 192);
  int lab = label[n];

  float sm = (x0.x + x0.y + x0.z + x0.w) + (x1.x + x1.y + x1.z + x1.w) +
             (x2.x + x2.y + x2.z + x2.w) + (x3.x + x3.y + x3.z + x3.w);
  float q = x0.x * x0.x + x0.y * x0.y + x0.z * x0.z + x0.w * x0.w +
            x1.x * x1.x + x1.y * x1.y + x1.z * x1.z + x1.w * x1.w +
            x2.x * x2.x + x2.y * x2.y + x2.z * x2.z + x2.w * x2.w +
            x3.x * x3.x + x3.y * x3.y + x3.z * x3.z + x3.w * x3.w;
  sm = wred16(sm); q = wred16(q);
  float mu = sm * (1.0f / 256.0f);
  float var = q * (1.0f / 256.0f) - mu * mu;
  float rstd = rsqrtf(var + LN_EPS);

  const float* gb = fng + s * 4;
  const float* bb = fnb + s * 4;
  const float4 g0 = *(const float4*)(gb);
  const float4 g1 = *(const float4*)(gb + 64);
  const float4 g2 = *(const float4*)(gb + 128);
  const float4 g3 = *(const float4*)(gb + 192);
  const float4 b0 = *(const float4*)(bb);
  const float4 b1 = *(const float4*)(bb + 64);
  const float4 b2 = *(const float4*)(bb + 128);
  const float4 b3 = *(const float4*)(bb + 192);

  float4 y0, y1, y2, y3;
  y0.x = (x0.x - mu) * rstd * g0.x + b0.x; y0.y = (x0.y - mu) * rstd * g0.y + b0.y;
  y0.z = (x0.z - mu) * rstd * g0.z + b0.z; y0.w = (x0.w - mu) * rstd * g0.w + b0.w;
  y1.x = (x1.x - mu) * rstd * g1.x + b1.x; y1.y = (x1.y - mu) * rstd * g1.y + b1.y;
  y1.z = (x1.z - mu) * rstd * g1.z + b1.z; y1.w = (x1.w - mu) * rstd * g1.w + b1.w;
  y2.x = (x2.x - mu) * rstd * g2.x + b2.x; y2.y = (x2.y - mu) * rstd * g2.y + b2.y;
  y2.z = (x2.z - mu) * rstd * g2.z + b2.z; y2.w = (x2.w - mu) * rstd * g2.w + b2.w;
  y3.x = (x3.x - mu) * rstd * g3.x + b3.x; y3.y = (x3.y - mu) * rstd * g3.y + b3.y;
  y3.z = (x3.z - mu) * rstd * g3.z + b3.z; y3.w = (x3.w - mu) * rstd * g3.w + b3.w;

  float qq = y0.x * y0.x + y0.y * y0.y + y0.z * y0.z + y0.w * y0.w +
             y1.x * y1.x + y1.y * y1.y + y1.z * y1.z + y1.w * y1.w +
             y2.x * y2.x + y2.y * y2.y + y2.z * y2.z + y2.w * y2.w +
             y3.x * y3.x + y3.y * y3.y + y3.z * y3.z + y3.w * y3.w;
  qq = wred16(qq);

  // 8 partial dots over this lane's 16 dims (swizzled LDS reads, conflict-free)
  float dot[8];
#pragma unroll
  for (int j = 0; j < 8; j++) {
    int jx = 4 * (j ^ (s & 7));
    const float4 pa = *(const float4*)(&prS[s * 32 + jx]);
    const float4 pb = *(const float4*)(&prS[(16 + s) * 32 + jx]);
    const float4 pc = *(const float4*)(&prS[(32 + s) * 32 + jx]);
    const float4 pd = *(const float4*)(&prS[(48 + s) * 32 + jx]);
    dot[j] = y0.x * pa.x + y0.y * pa.y + y0.z * pa.z + y0.w * pa.w +
             y1.x * pb.x + y1.y * pb.y + y1.z * pb.z + y1.w * pb.w +
             y2.x * pc.x + y2.y * pc.y + y2.z * pc.z + y2.w * pc.w +
             y3.x * pd.x + y3.y * pd.y + y3.z * pd.z + y3.w * pd.w;
  }
  // transpose-reduce: 8 shuffles total (was 25). Lane s ends with full dot[s&7].
  int b0s = s & 1, b1s = (s >> 1) & 1, b2s = (s >> 2) & 1;
  float e0 = b0s ? dot[1] : dot[0], o0 = b0s ? dot[0] : dot[1];
  float e1 = b0s ? dot[3] : dot[2], o1 = b0s ? dot[2] : dot[3];
  float e2 = b0s ? dot[5] : dot[4], o2 = b0s ? dot[4] : dot[5];
  float e3 = b0s ? dot[7] : dot[6], o3 = b0s ? dot[6] : dot[7];
  e0 += __shfl_xor(o0, 1, 64);
  e1 += __shfl_xor(o1, 1, 64);
  e2 += __shfl_xor(o2, 1, 64);
  e3 += __shfl_xor(o3, 1, 64);
  float f0 = b1s ? e1 : e0, p0 = b1s ? e0 : e1;
  float f1 = b1s ? e3 : e2, p1 = b1s ? e2 : e3;
  f0 += __shfl_xor(p0, 2, 64);
  f1 += __shfl_xor(p1, 2, 64);
  float h = b2s ? f1 : f0, ph = b2s ? f0 : f1;
  h += __shfl_xor(ph, 4, 64);
  float v = h + __shfl_xor(h, 8, 64);

  float invq = 1.0f / fmaxf(sqrtf(qq), 1e-12f);
  float d = v * invq;   // lane s (and s+8) holds dot j = s&7 = (k=s>>1, m=s&1)

  if (s < 8) out_logits[(size_t)n * 8 + ((s & 1) << 2) + (s >> 1)] = d;

  // nearest: nr_k = max over m; lanes 2k,2k+1 both end with nr_k
  float nm = fmaxf(d, __shfl_xor(d, 1, 64));
  float tA = __shfl_xor(nm, 2, 64);
  float s2 = nm + tA, q2 = nm * nm + tA * tA;
  float s4 = s2 + __shfl_xor(s2, 4, 64);
  float q4 = q2 + __shfl_xor(q2, 4, 64);
  float m4 = 0.25f * s4;
  float v4 = 0.25f * q4 - m4 * m4;
  float rs4 = rsqrtf(v4 + LN_EPS);
  int k = (s >> 1) & 3;
  float lnv = (nm - m4) * rs4 * mng[k] + mnb[k];

  int bimg = n / HWIMG;
  int p = n - bimg * HWIMG;
  if (s < 8 && (s & 1) == 0)
    out_nearest[((size_t)bimg * 4 + k) * HWIMG + p] = lnv;

  // argmax over k with tie -> lowest k
  float av = lnv; int ak = k;
#pragma unroll
  for (int o = 2; o <= 4; o <<= 1) {
    float ov = __shfl_xor(av, o, 64);
    int ok = __shfl_xor(ak, o, 64);
    bool take = (ov > av) || (ov == av && ok < ak);
    av = take ? ov : av;
    ak = take ? ok : ak;
  }

  // ---- fused sinkhorn iter-1 (R0, cnt4) + E cache ----
  float Ev = expf(d / 0.05f);
  bool isLab = (s < 8) && ((s >> 1) == lab);
  if (isLab) ((float*)(ws->E2 + n))[s & 1] = Ev;
  float val = isLab ? Ev : 0.f;
  val += __shfl_xor(val, 16, 64);
  val += __shfl_xor(val, 32, 64);
  unsigned cu = ((s < 8) && !(s & 1) && ((s >> 1) == lab)) ? 1u : 0u;
  cu += (unsigned)__shfl_xor((int)cu, 16, 64);
  cu += (unsigned)__shfl_xor((int)cu, 32, 64);
  if (lane < 8) sR4[wave][lane] = val;
  if (lane < 8 && !(lane & 1)) sC4[wave][lane >> 1] = cu;

  // ---- compact correct-pixel list ----
  bool corr = (s == 0) && (lab == ak);
  if (corr) { unsigned pos = atomicAdd(&sCorr, 1u); sList[pos] = n; }
  __syncthreads();
  if (tid == 0) sBase = atomicAdd(&ws->nCorr, sCorr);
  if (tid < 8) {
    double rs = (double)sR4[0][tid] + (double)sR4[1][tid] +
                (double)sR4[2][tid] + (double)sR4[3][tid];
    unsafeAtomicAdd(&ws->R[0][tid], rs);
  }
  if (tid < 4) {
    unsigned cs = sC4[0][tid] + sC4[1][tid] + sC4[2][tid] + sC4[3][tid];
    if (cs) atomicAdd(&ws->cnt4[tid], cs);
  }
  __syncthreads();
  if (tid < sCorr) ws->corrList[sBase + tid] = sList[tid];
}

// ---------------- K2: sinkhorn reduction pass (iter 2,3) ----------------
// reads cached E2 (8 B/pixel) instead of logits (32 B/pixel)
template <int ITER>
__global__ __launch_bounds__(256) void k_sink(const int* __restrict__ label,
                                              Ws* __restrict__ ws) {
  __shared__ float su1[8], su2[8], sBn[4];
  int tid = threadIdx.x;
  if (tid < 8) {
    int c = tid >> 1;
    float S = (float)ws->R[0][c * 2] + (float)ws->R[0][c * 2 + 1];
    float uu0 = 1.0f / fmaxf(S, 1e-30f);
    float R0 = (float)ws->R[0][tid];
    float uu1 = uu0 / (fmaxf(uu0 * R0, 1e-30f) * 2.0f);
    su1[tid] = uu1;
    if (ITER >= 3) {
      float R1 = (float)ws->R[1][tid];
      su2[tid] = uu1 / (fmaxf(uu1 * R1, 1e-30f) * 2.0f);
    }
  }
  if (tid < 4) sBn[tid] = fmaxf((float)ws->cnt4[tid], 1.0f);
  __syncthreads();

  double a0 = 0, a1 = 0, a2 = 0, a3 = 0, a4 = 0, a5 = 0, a6 = 0, a7 = 0;
  int gtid = blockIdx.x * 256 + tid;
  int T = gridDim.x * 256;
  for (int n = gtid; n < N_PIX; n += T) {
    int c = label[n];
    float2 e = ws->E2[n];
    float E0 = e.x, E1 = e.y;
    float S1 = su1[c * 2] * E0 + su1[c * 2 + 1] * E1;
    float v1 = 1.0f / (fmaxf(S1, 1e-30f) * sBn[c]);
    float v = v1;
    if (ITER >= 3) {
      float S2 = su2[c * 2] * E0 + su2[c * 2 + 1] * E1;
      v = v1 / (fmaxf(v1 * S2, 1e-30f) * sBn[c]);
    }
    double t0 = (double)(v * E0), t1 = (double)(v * E1);
    if (c == 0) { a0 += t0; a1 += t1; }
    else if (c == 1) { a2 += t0; a3 += t1; }
    else if (c == 2) { a4 += t0; a5 += t1; }
    else { a6 += t0; a7 += t1; }
  }
  a0 = wredd(a0); a1 = wredd(a1); a2 = wredd(a2); a3 = wredd(a3);
  a4 = wredd(a4); a5 = wredd(a5); a6 = wredd(a6); a7 = wredd(a7);
  __shared__ double lds[4][8];
  int wave = tid >> 6, lane = tid & 63;
  if (lane == 0) {
    lds[wave][0] = a0; lds[wave][1] = a1; lds[wave][2] = a2; lds[wave][3] = a3;
    lds[wave][4] = a4; lds[wave][5] = a5; lds[wave][6] = a6; lds[wave][7] = a7;
  }
  __syncthreads();
  if (tid < 8) {
    double ssum = lds[0][tid] + lds[1][tid] + lds[2][tid] + lds[3][tid];
    unsafeAtomicAdd(&ws->R[ITER - 1][tid], ssum);
  }
}

// ---------------- K3: proto_target (all pixels) + dense gather over corrList ----
__global__ __launch_bounds__(256) void k_accum(
    const float* __restrict__ X, const int* __restrict__ label,
    const float* __restrict__ fng, const float* __restrict__ fnb,
    Ws* __restrict__ ws, float* __restrict__ out_target) {
  __shared__ float fa[4 * 2048];  // per-wave f accumulator copies (32 KB)
  __shared__ float su[8];
  __shared__ unsigned ldc[4][8];
  int tid = threadIdx.x;
  if (tid < 8) {
    int c = tid >> 1;
    float S = (float)ws->R[0][c * 2] + (float)ws->R[0][c * 2 + 1];
    float uu0 = 1.0f / fmaxf(S, 1e-30f);
    float R0 = (float)ws->R[0][tid];
    float uu1 = uu0 / (fmaxf(uu0 * R0, 1e-30f) * 2.0f);
    float R1 = (float)ws->R[1][tid];
    float uu2 = uu1 / (fmaxf(uu1 * R1, 1e-30f) * 2.0f);
    float R2 = (float)ws->R[2][tid];
    su[tid] = uu2 / (fmaxf(uu2 * R2, 1e-30f) * 2.0f);
  }
  for (int i = tid; i < 4 * 2048; i += 256) fa[i] = 0.f;
  __syncthreads();

  // phase A: proto_target for every pixel (streaming)
  int gtid = blockIdx.x * 256 + tid;
  int T = gridDim.x * 256;
  for (int n = gtid; n < N_PIX; n += T) {
    int c = label[n];
    float2 e = ws->E2[n];
    int idx = (su[c * 2 + 1] * e.y > su[c * 2] * e.x) ? 1 : 0;
    out_target[n] = (float)(idx + 2 * c);
  }

  // phase B: dense gather of correct pixels, 4 per wave-iteration
  int wave = tid >> 6, lane = tid & 63;
  const float4 g4 = *(const float4*)(fng + lane * 4);
  const float4 b4 = *(const float4*)(fnb + lane * 4);
  float* myAcc = &fa[wave * 2048];
  unsigned cl[8] = {0, 0, 0, 0, 0, 0, 0, 0};
  unsigned nc = ws->nCorr;
  unsigned gw = blockIdx.x * 4 + wave;
  unsigned GW = gridDim.x * 4;
  for (unsigned base = gw * 4; base < nc; base += GW * 4) {
    int m = (int)min(4u, nc - base);
    int bk[4]; float4 xx[4];
#pragma unroll
    for (int g = 0; g < 4; g++) if (g < m) {
      int n = ws->corrList[base + g];
      int c = label[n];
      float2 e = ws->E2[n];
      int idx = (su[c * 2 + 1] * e.y > su[c * 2] * e.x) ? 1 : 0;
      bk[g] = c * 2 + idx;
      xx[g] = *(const float4*)(X + (size_t)n * 256 + lane * 4);
    }
    float svr[4], qvr[4];
#pragma unroll
    for (int g = 0; g < 4; g++) if (g < m) {
      float4 x = xx[g];
      float sv = x.x + x.y + x.z + x.w;
      float qv = x.x * x.x + x.y * x.y + x.z * x.z + x.w * x.w;
      svr[g] = wredf(sv); qvr[g] = wredf(qv);
    }
    float4 yy[4]; float qqr[4];
#pragma unroll
    for (int g = 0; g < 4; g++) if (g < m) {
      float mu = svr[g] * (1.0f / 256.0f);
      float var = qvr[g] * (1.0f / 256.0f) - mu * mu;
      float rstd = rsqrtf(var + LN_EPS);
      float4 x = xx[g];
      float4 y;
      y.x = (x.x - mu) * rstd * g4.x + b4.x;
      y.y = (x.y - mu) * rstd * g4.y + b4.y;
      y.z = (x.z - mu) * rstd * g4.z + b4.z;
      y.w = (x.w - mu) * rstd * g4.w + b4.w;
      yy[g] = y;
      qqr[g] = wredf(y.x * y.x + y.y * y.y + y.z * y.z + y.w * y.w);
    }
#pragma unroll
    for (int g = 0; g < 4; g++) if (g < m) {
      float invq = 1.0f / fmaxf(sqrtf(qqr[g]), 1e-12f);
      float4 y = yy[g];
      float* dst = myAcc + bk[g] * 256 + lane * 4;
      dst[0] += y.x * invq; dst[1] += y.y * invq;
      dst[2] += y.z * invq; dst[3] += y.w * invq;
      if (lane == 0) cl[bk[g]]++;
    }
  }
  if (lane == 0) {
#pragma unroll
    for (int j = 0; j < 8; j++) ldc[wave][j] = cl[j];
  }
  __syncthreads();
  float* fg = &ws->fAcc[0][0];
  for (int i = tid; i < 2048; i += 256) {
    float ssum = fa[i] + fa[2048 + i] + fa[4096 + i] + fa[6144 + i];
    unsafeAtomicAdd(fg + i, ssum);
  }
  if (tid < 8) {
    unsigned cs = ldc[0][tid] + ldc[1][tid] + ldc[2][tid] + ldc[3][tid];
    if (cs) atomicAdd(&ws->nmk[tid], cs);
  }
}

// ---------------- K4: finalize prototypes ----------------
__global__ __launch_bounds__(512) void k_final(Ws* __restrict__ ws, float* __restrict__ out_protos) {
  int tid = threadIdx.x;
  int r = tid >> 6, lane = tid & 63;
  const float4 f = *(const float4*)(&ws->fAcc[r][lane * 4]);
  float ss = wredf(f.x * f.x + f.y * f.y + f.z * f.z + f.w * f.w);
  float invf = 1.0f / fmaxf(sqrtf(ss), 1e-12f);
  unsigned nr = ws->nmk[r];
  int c = r >> 1;
  unsigned tot = ws->nmk[c * 2] + ws->nmk[c * 2 + 1];
  bool cond = (tot > 0u) && (nr != 0u);
  const float4 p = *(const float4*)(&ws->protoN[r][lane * 4]);
  float u0 = cond ? 0.999f * p.x + 0.001f * (f.x * invf) : p.x;
  float u1 = cond ? 0.999f * p.y + 0.001f * (f.y * invf) : p.y;
  float u2 = cond ? 0.999f * p.z + 0.001f * (f.z * invf) : p.z;
  float u3 = cond ? 0.999f * p.w + 0.001f * (f.w * invf) : p.w;
  float ss2 = wredf(u0 * u0 + u1 * u1 + u2 * u2 + u3 * u3);
  float invn = 1.0f / fmaxf(sqrtf(ss2), 1e-12f);
  float4 o; o.x = u0 * invn; o.y = u1 * invn; o.z = u2 * invn; o.w = u3 * invn;
  *(float4*)(out_protos + r * 256 + lane * 4) = o;
}

// ---------------- launch ----------------
extern "C" void kernel_launch(void* const* d_in, const int* in_sizes, int n_in,
                              void* d_out, int out_size, void* d_ws, size_t ws_size,
                              hipStream_t stream) {
  const float* X = (const float*)d_in[0];
  const int* label = (const int*)d_in[1];
  const float* protos = (const float*)d_in[2];
  const float* fng = (const float*)d_in[3];
  const float* fnb = (const float*)d_in[4];
  const float* mng = (const float*)d_in[5];
  const float* mnb = (const float*)d_in[6];

  float* out = (float*)d_out;
  float* out_nearest = out;                        // 32*4*12544 = 1605632
  float* out_logits = out + 1605632;               // N*8 = 3211264
  float* out_target = out_logits + 3211264;        // N
  float* out_protos = out_target + N_PIX;          // 2048
  Ws* ws = (Ws*)d_ws;

  k_zero<<<1, 256, 0, stream>>>(ws);
  k_main<<<N_PIX / 16, 256, 0, stream>>>(X, label, protos, fng, fnb, mng, mnb, ws, out_nearest, out_logits);
  k_sink<2><<<512, 256, 0, stream>>>(label, ws);
  k_sink<3><<<512, 256, 0, stream>>>(label, ws);
  k_accum<<<512, 256, 0, stream>>>(X, label, fng, fnb, ws, out_target);
  k_final<<<1, 512, 0, stream>>>(ws, out_protos);
}

// Round 3
// 721.041 us; speedup vs baseline: 1.5531x; 1.5531x over previous
//
#include <hip/hip_runtime.h>
#include <stdint.h>

#define N_PIX 401408
#define HWIMG 12544   // 112*112
#define LN_EPS 1e-5f
#define NBLK 3136     // k_main blocks
#define ITERS 8       // pixel-iterations per block (16 pixels each)

// ---------------- workspace layout (3.71 MB) ----------------
struct Ws {
  double R[3][8];            // sinkhorn row sums per iter, [iter][c*2+m]
  unsigned cnt4[4];          // class pixel counts (Bn)
  unsigned nmk[8];           // correct counts per (c,m)
  unsigned pad[4];
  float  protoN[8][256];     // l2-normalized prototypes, row r = c*2+m
  float  fAcc[8][256];       // f accumulator
  double   partR[NBLK][8];   // per-block R0 partials (plain stores, no atomics)
  unsigned partC[NBLK][4];   // per-block class-count partials
  unsigned partNc[NBLK];     // per-block correct-pixel count
  unsigned char corrTmp[NBLK][128]; // per-block correct-pixel offsets (n = b*128+off)
  float2 E2[N_PIX];          // exp(sim/eps) for label class, (m=0, m=1)
};

// ---------------- reductions ----------------
__device__ __forceinline__ float wredf(float v) {   // full 64-lane
#pragma unroll
  for (int o = 32; o > 0; o >>= 1) v += __shfl_xor(v, o, 64);
  return v;
}
__device__ __forceinline__ float wred16(float v) {  // within 16-lane group
  v += __shfl_xor(v, 1, 64);
  v += __shfl_xor(v, 2, 64);
  v += __shfl_xor(v, 4, 64);
  v += __shfl_xor(v, 8, 64);
  return v;
}
__device__ __forceinline__ double wredd(double v) {
#pragma unroll
  for (int o = 32; o > 0; o >>= 1) v += __shfl_xor(v, o, 64);
  return v;
}
__device__ __forceinline__ unsigned wredu(unsigned v) {
#pragma unroll
  for (int o = 32; o > 0; o >>= 1) v += (unsigned)__shfl_xor((int)v, o, 64);
  return v;
}

// ---------------- K1: per-pixel main ----------------
// 16 lanes per pixel, 4 pixels per wave, 16 pixels per block-iteration,
// 8 iterations per block. NO global atomics: per-block partials via stores.
__global__ __launch_bounds__(256) void k_main(
    const float* __restrict__ X, const int* __restrict__ label,
    const float* __restrict__ protos,
    const float* __restrict__ fng, const float* __restrict__ fnb,
    const float* __restrict__ mng, const float* __restrict__ mnb,
    Ws* __restrict__ ws,
    float* __restrict__ out_nearest, float* __restrict__ out_logits) {
  __shared__ float prS[2048];
  __shared__ double sRd[4][8];
  __shared__ unsigned sC4[4][4];
  __shared__ unsigned sCorr;
  __shared__ unsigned char sList[128];
  int tid = threadIdx.x;
  int wave = tid >> 6, lane = tid & 63;
  if (tid == 0) sCorr = 0u;

  // normalize prototypes into swizzled LDS (each wave does rows w, w+4)
#pragma unroll
  for (int t = 0; t < 2; t++) {
    int r = wave + t * 4;
    const float4 p = *(const float4*)(protos + r * 256 + lane * 4);
    float ss = p.x * p.x + p.y * p.y + p.z * p.z + p.w * p.w;
    ss = wredf(ss);
    float inv = 1.0f / fmaxf(sqrtf(ss), 1e-12f);
    float4 o; o.x = p.x * inv; o.y = p.y * inv; o.z = p.z * inv; o.w = p.w * inv;
    *(float4*)(&prS[lane * 32 + 4 * (r ^ (lane & 7))]) = o;
    if (blockIdx.x == 0) *(float4*)(&ws->protoN[r][lane * 4]) = o;
  }
  __syncthreads();

  int grp = lane >> 4, s = lane & 15;

  // hoisted per-lane constants (live across the whole loop)
  const float* gb = fng + s * 4;
  const float* bb = fnb + s * 4;
  const float4 g0 = *(const float4*)(gb);
  const float4 g1 = *(const float4*)(gb + 64);
  const float4 g2 = *(const float4*)(gb + 128);
  const float4 g3 = *(const float4*)(gb + 192);
  const float4 b0 = *(const float4*)(bb);
  const float4 b1 = *(const float4*)(bb + 64);
  const float4 b2 = *(const float4*)(bb + 128);
  const float4 b3 = *(const float4*)(bb + 192);
  int k = (s >> 1) & 3;
  float mngk = mng[k], mnbk = mnb[k];

  double rAcc = 0.0;      // lanes 0..7 meaningful: R0 partial for (c,m)=lane
  unsigned cAcc = 0u;     // lanes 0,2,4,6 meaningful: class counts

  for (int it = 0; it < ITERS; ++it) {
    int n = blockIdx.x * (16 * ITERS) + it * 16 + wave * 4 + grp;

    const float* xb = X + (size_t)n * 256 + s * 4;
    const float4 x0 = *(const float4*)(xb);         // dims 4s..4s+3
    const float4 x1 = *(const float4*)(xb + 64);
    const float4 x2 = *(const float4*)(xb + 128);
    const float4 x3 = *(const float4*)(xb + 192);
    int lab = label[n];

    float sm = (x0.x + x0.y + x0.z + x0.w) + (x1.x + x1.y + x1.z + x1.w) +
               (x2.x + x2.y + x2.z + x2.w) + (x3.x + x3.y + x3.z + x3.w);
    float q = x0.x * x0.x + x0.y * x0.y + x0.z * x0.z + x0.w * x0.w +
              x1.x * x1.x + x1.y * x1.y + x1.z * x1.z + x1.w * x1.w +
              x2.x * x2.x + x2.y * x2.y + x2.z * x2.z + x2.w * x2.w +
              x3.x * x3.x + x3.y * x3.y + x3.z * x3.z + x3.w * x3.w;
    sm = wred16(sm); q = wred16(q);
    float mu = sm * (1.0f / 256.0f);
    float var = q * (1.0f / 256.0f) - mu * mu;
    float rstd = rsqrtf(var + LN_EPS);

    float4 y0, y1, y2, y3;
    y0.x = (x0.x - mu) * rstd * g0.x + b0.x; y0.y = (x0.y - mu) * rstd * g0.y + b0.y;
    y0.z = (x0.z - mu) * rstd * g0.z + b0.z; y0.w = (x0.w - mu) * rstd * g0.w + b0.w;
    y1.x = (x1.x - mu) * rstd * g1.x + b1.x; y1.y = (x1.y - mu) * rstd * g1.y + b1.y;
    y1.z = (x1.z - mu) * rstd * g1.z + b1.z; y1.w = (x1.w - mu) * rstd * g1.w + b1.w;
    y2.x = (x2.x - mu) * rstd * g2.x + b2.x; y2.y = (x2.y - mu) * rstd * g2.y + b2.y;
    y2.z = (x2.z - mu) * rstd * g2.z + b2.z; y2.w = (x2.w - mu) * rstd * g2.w + b2.w;
    y3.x = (x3.x - mu) * rstd * g3.x + b3.x; y3.y = (x3.y - mu) * rstd * g3.y + b3.y;
    y3.z = (x3.z - mu) * rstd * g3.z + b3.z; y3.w = (x3.w - mu) * rstd * g3.w + b3.w;

    float qq = y0.x * y0.x + y0.y * y0.y + y0.z * y0.z + y0.w * y0.w +
               y1.x * y1.x + y1.y * y1.y + y1.z * y1.z + y1.w * y1.w +
               y2.x * y2.x + y2.y * y2.y + y2.z * y2.z + y2.w * y2.w +
               y3.x * y3.x + y3.y * y3.y + y3.z * y3.z + y3.w * y3.w;
    qq = wred16(qq);

    // 8 partial dots over this lane's 16 dims (swizzled LDS, conflict-free)
    float dot[8];
#pragma unroll
    for (int j = 0; j < 8; j++) {
      int jx = 4 * (j ^ (s & 7));
      const float4 pa = *(const float4*)(&prS[s * 32 + jx]);
      const float4 pb = *(const float4*)(&prS[(16 + s) * 32 + jx]);
      const float4 pc = *(const float4*)(&prS[(32 + s) * 32 + jx]);
      const float4 pd = *(const float4*)(&prS[(48 + s) * 32 + jx]);
      dot[j] = y0.x * pa.x + y0.y * pa.y + y0.z * pa.z + y0.w * pa.w +
               y1.x * pb.x + y1.y * pb.y + y1.z * pb.z + y1.w * pb.w +
               y2.x * pc.x + y2.y * pc.y + y2.z * pc.z + y2.w * pc.w +
               y3.x * pd.x + y3.y * pd.y + y3.z * pd.z + y3.w * pd.w;
    }
    // transpose-reduce: 8 shuffles total. Lane s ends with full dot[s&7].
    int b0s = s & 1, b1s = (s >> 1) & 1, b2s = (s >> 2) & 1;
    float e0 = b0s ? dot[1] : dot[0], o0 = b0s ? dot[0] : dot[1];
    float e1 = b0s ? dot[3] : dot[2], o1 = b0s ? dot[2] : dot[3];
    float e2 = b0s ? dot[5] : dot[4], o2 = b0s ? dot[4] : dot[5];
    float e3 = b0s ? dot[7] : dot[6], o3 = b0s ? dot[6] : dot[7];
    e0 += __shfl_xor(o0, 1, 64);
    e1 += __shfl_xor(o1, 1, 64);
    e2 += __shfl_xor(o2, 1, 64);
    e3 += __shfl_xor(o3, 1, 64);
    float f0 = b1s ? e1 : e0, p0 = b1s ? e0 : e1;
    float f1 = b1s ? e3 : e2, p1 = b1s ? e2 : e3;
    f0 += __shfl_xor(p0, 2, 64);
    f1 += __shfl_xor(p1, 2, 64);
    float h = b2s ? f1 : f0, ph = b2s ? f0 : f1;
    h += __shfl_xor(ph, 4, 64);
    float v = h + __shfl_xor(h, 8, 64);

    float invq = 1.0f / fmaxf(sqrtf(qq), 1e-12f);
    float d = v * invq;   // lane s (and s+8) holds dot j = s&7 = (k=s>>1, m=s&1)

    if (s < 8) out_logits[(size_t)n * 8 + ((s & 1) << 2) + (s >> 1)] = d;

    // nearest: nr_k = max over m; lanes 2k,2k+1 both end with nr_k
    float nm = fmaxf(d, __shfl_xor(d, 1, 64));
    float tA = __shfl_xor(nm, 2, 64);
    float s2 = nm + tA, q2 = nm * nm + tA * tA;
    float s4 = s2 + __shfl_xor(s2, 4, 64);
    float q4 = q2 + __shfl_xor(q2, 4, 64);
    float m4 = 0.25f * s4;
    float v4 = 0.25f * q4 - m4 * m4;
    float rs4 = rsqrtf(v4 + LN_EPS);
    float lnv = (nm - m4) * rs4 * mngk + mnbk;

    int bimg = n / HWIMG;
    int p = n - bimg * HWIMG;
    if (s < 8 && (s & 1) == 0)
      out_nearest[((size_t)bimg * 4 + k) * HWIMG + p] = lnv;

    // argmax over k with tie -> lowest k
    float av = lnv; int ak = k;
#pragma unroll
    for (int o = 2; o <= 4; o <<= 1) {
      float ov = __shfl_xor(av, o, 64);
      int ok = __shfl_xor(ak, o, 64);
      bool take = (ov > av) || (ov == av && ok < ak);
      av = take ? ov : av;
      ak = take ? ok : ak;
    }

    // ---- fused sinkhorn iter-1 partials (register accumulation) ----
    float Ev = expf(d / 0.05f);
    bool isLab = (s < 8) && ((s >> 1) == lab);
    if (isLab) ((float*)(ws->E2 + n))[s & 1] = Ev;
    float val = isLab ? Ev : 0.f;
    val += __shfl_xor(val, 16, 64);
    val += __shfl_xor(val, 32, 64);
    rAcc += (double)val;
    unsigned cu = ((s < 8) && !(s & 1) && ((s >> 1) == lab)) ? 1u : 0u;
    cu += (unsigned)__shfl_xor((int)cu, 16, 64);
    cu += (unsigned)__shfl_xor((int)cu, 32, 64);
    cAcc += cu;

    // ---- push correct pixel into per-block LDS list (offset in [0,128)) ----
    if (s == 0 && lab == ak) {
      unsigned pos = atomicAdd(&sCorr, 1u);
      sList[pos] = (unsigned char)(it * 16 + wave * 4 + grp);
    }
  }

  // epilogue: per-block partials (plain global stores, no atomics)
  if (lane < 8) sRd[wave][lane] = rAcc;
  if (lane < 8 && !(lane & 1)) sC4[wave][lane >> 1] = cAcc;
  __syncthreads();
  if (tid < 8)
    ws->partR[blockIdx.x][tid] = sRd[0][tid] + sRd[1][tid] + sRd[2][tid] + sRd[3][tid];
  if (tid < 4)
    ws->partC[blockIdx.x][tid] = sC4[0][tid] + sC4[1][tid] + sC4[2][tid] + sC4[3][tid];
  unsigned nc = sCorr;
  if (tid == 0) ws->partNc[blockIdx.x] = nc;
  if (tid < (int)nc) ws->corrTmp[blockIdx.x][tid] = sList[tid];
}

// ---------------- K2: reduce per-block partials (no atomics) ----------------
// blocks 0..7: R[0][b]; blocks 8..11: cnt4[b-8]; blocks 0/1 also zero state.
__global__ __launch_bounds__(256) void k_red(Ws* __restrict__ ws) {
  __shared__ double ld[4];
  __shared__ unsigned lu[4];
  int b = blockIdx.x;
  int tid = threadIdx.x;
  int wave = tid >> 6, lane = tid & 63;
  if (b < 8) {
    double acc = 0.0;
    for (int r = tid; r < NBLK; r += 256) acc += ws->partR[r][b];
    acc = wredd(acc);
    if (lane == 0) ld[wave] = acc;
    __syncthreads();
    if (tid == 0) ws->R[0][b] = ld[0] + ld[1] + ld[2] + ld[3];
    if (b == 0) {
      if (tid < 16) ((double*)ws->R)[8 + tid] = 0.0;   // zero R[1], R[2]
      if (tid >= 16 && tid < 24) ws->nmk[tid - 16] = 0u;
    }
    if (b == 1) {
      for (int i = tid; i < 2048; i += 256) (&ws->fAcc[0][0])[i] = 0.f;
    }
  } else {
    int j = b - 8;
    unsigned acc = 0u;
    for (int r = tid; r < NBLK; r += 256) acc += ws->partC[r][j];
    acc = wredu(acc);
    if (lane == 0) lu[wave] = acc;
    __syncthreads();
    if (tid == 0) ws->cnt4[j] = lu[0] + lu[1] + lu[2] + lu[3];
  }
}

// ---------------- K3: sinkhorn reduction pass (iter 2,3) ----------------
// reads cached E2 (8 B/pixel)
template <int ITER>
__global__ __launch_bounds__(256) void k_sink(const int* __restrict__ label,
                                              Ws* __restrict__ ws) {
  __shared__ float su1[8], su2[8], sBn[4];
  int tid = threadIdx.x;
  if (tid < 8) {
    int c = tid >> 1;
    float S = (float)ws->R[0][c * 2] + (float)ws->R[0][c * 2 + 1];
    float uu0 = 1.0f / fmaxf(S, 1e-30f);
    float R0 = (float)ws->R[0][tid];
    float uu1 = uu0 / (fmaxf(uu0 * R0, 1e-30f) * 2.0f);
    su1[tid] = uu1;
    if (ITER >= 3) {
      float R1 = (float)ws->R[1][tid];
      su2[tid] = uu1 / (fmaxf(uu1 * R1, 1e-30f) * 2.0f);
    }
  }
  if (tid < 4) sBn[tid] = fmaxf((float)ws->cnt4[tid], 1.0f);
  __syncthreads();

  double a0 = 0, a1 = 0, a2 = 0, a3 = 0, a4 = 0, a5 = 0, a6 = 0, a7 = 0;
  int gtid = blockIdx.x * 256 + tid;
  int T = gridDim.x * 256;
  for (int n = gtid; n < N_PIX; n += T) {
    int c = label[n];
    float2 e = ws->E2[n];
    float E0 = e.x, E1 = e.y;
    float S1 = su1[c * 2] * E0 + su1[c * 2 + 1] * E1;
    float v1 = 1.0f / (fmaxf(S1, 1e-30f) * sBn[c]);
    float v = v1;
    if (ITER >= 3) {
      float S2 = su2[c * 2] * E0 + su2[c * 2 + 1] * E1;
      v = v1 / (fmaxf(v1 * S2, 1e-30f) * sBn[c]);
    }
    double t0 = (double)(v * E0), t1 = (double)(v * E1);
    if (c == 0) { a0 += t0; a1 += t1; }
    else if (c == 1) { a2 += t0; a3 += t1; }
    else if (c == 2) { a4 += t0; a5 += t1; }
    else { a6 += t0; a7 += t1; }
  }
  a0 = wredd(a0); a1 = wredd(a1); a2 = wredd(a2); a3 = wredd(a3);
  a4 = wredd(a4); a5 = wredd(a5); a6 = wredd(a6); a7 = wredd(a7);
  __shared__ double lds[4][8];
  int wave = tid >> 6, lane = tid & 63;
  if (lane == 0) {
    lds[wave][0] = a0; lds[wave][1] = a1; lds[wave][2] = a2; lds[wave][3] = a3;
    lds[wave][4] = a4; lds[wave][5] = a5; lds[wave][6] = a6; lds[wave][7] = a7;
  }
  __syncthreads();
  if (tid < 8) {
    double ssum = lds[0][tid] + lds[1][tid] + lds[2][tid] + lds[3][tid];
    unsafeAtomicAdd(&ws->R[ITER - 1][tid], ssum);   // only 512 blocks: cheap
  }
}

// ---------------- K4: proto_target (all pixels) + per-chunk gather ----------
__global__ __launch_bounds__(256) void k_accum(
    const float* __restrict__ X, const int* __restrict__ label,
    const float* __restrict__ fng, const float* __restrict__ fnb,
    Ws* __restrict__ ws, float* __restrict__ out_target) {
  __shared__ float fa[4 * 2048];  // per-wave f accumulator copies (32 KB)
  __shared__ float su[8];
  __shared__ unsigned ldc[4][8];
  int tid = threadIdx.x;
  if (tid < 8) {
    int c = tid >> 1;
    float S = (float)ws->R[0][c * 2] + (float)ws->R[0][c * 2 + 1];
    float uu0 = 1.0f / fmaxf(S, 1e-30f);
    float R0 = (float)ws->R[0][tid];
    float uu1 = uu0 / (fmaxf(uu0 * R0, 1e-30f) * 2.0f);
    float R1 = (float)ws->R[1][tid];
    float uu2 = uu1 / (fmaxf(uu1 * R1, 1e-30f) * 2.0f);
    float R2 = (float)ws->R[2][tid];
    su[tid] = uu2 / (fmaxf(uu2 * R2, 1e-30f) * 2.0f);
  }
  for (int i = tid; i < 4 * 2048; i += 256) fa[i] = 0.f;
  __syncthreads();

  // phase A: proto_target for every pixel (streaming)
  int gtid = blockIdx.x * 256 + tid;
  int T = gridDim.x * 256;
  for (int n = gtid; n < N_PIX; n += T) {
    int c = label[n];
    float2 e = ws->E2[n];
    int idx = (su[c * 2 + 1] * e.y > su[c * 2] * e.x) ? 1 : 0;
    out_target[n] = (float)(idx + 2 * c);
  }

  // phase B: per-chunk dense gather of correct pixels, 4 per wave-iteration
  int wave = tid >> 6, lane = tid & 63;
  const float4 g4 = *(const float4*)(fng + lane * 4);
  const float4 b4 = *(const float4*)(fnb + lane * 4);
  float* myAcc = &fa[wave * 2048];
  unsigned cl[8] = {0, 0, 0, 0, 0, 0, 0, 0};
  unsigned gw = blockIdx.x * 4 + wave;
  unsigned GW = gridDim.x * 4;
  for (unsigned b = gw; b < NBLK; b += GW) {
    unsigned cnt = ws->partNc[b];
    const unsigned char* lst = ws->corrTmp[b];
    for (unsigned base = 0; base < cnt; base += 4) {
      int m = (int)min(4u, cnt - base);
      int bk[4]; float4 xx[4];
#pragma unroll
      for (int g = 0; g < 4; g++) if (g < m) {
        int n = (int)(b * 128u) + (int)lst[base + g];
        int c = label[n];
        float2 e = ws->E2[n];
        int idx = (su[c * 2 + 1] * e.y > su[c * 2] * e.x) ? 1 : 0;
        bk[g] = c * 2 + idx;
        xx[g] = *(const float4*)(X + (size_t)n * 256 + lane * 4);
      }
      float svr[4], qvr[4];
#pragma unroll
      for (int g = 0; g < 4; g++) if (g < m) {
        float4 x = xx[g];
        float sv = x.x + x.y + x.z + x.w;
        float qv = x.x * x.x + x.y * x.y + x.z * x.z + x.w * x.w;
        svr[g] = wredf(sv); qvr[g] = wredf(qv);
      }
      float4 yy[4]; float qqr[4];
#pragma unroll
      for (int g = 0; g < 4; g++) if (g < m) {
        float mu = svr[g] * (1.0f / 256.0f);
        float var = qvr[g] * (1.0f / 256.0f) - mu * mu;
        float rstd = rsqrtf(var + LN_EPS);
        float4 x = xx[g];
        float4 y;
        y.x = (x.x - mu) * rstd * g4.x + b4.x;
        y.y = (x.y - mu) * rstd * g4.y + b4.y;
        y.z = (x.z - mu) * rstd * g4.z + b4.z;
        y.w = (x.w - mu) * rstd * g4.w + b4.w;
        yy[g] = y;
        qqr[g] = wredf(y.x * y.x + y.y * y.y + y.z * y.z + y.w * y.w);
      }
#pragma unroll
      for (int g = 0; g < 4; g++) if (g < m) {
        float invq = 1.0f / fmaxf(sqrtf(qqr[g]), 1e-12f);
        float4 y = yy[g];
        float* dst = myAcc + bk[g] * 256 + lane * 4;
        dst[0] += y.x * invq; dst[1] += y.y * invq;
        dst[2] += y.z * invq; dst[3] += y.w * invq;
        if (lane == 0) cl[bk[g]]++;
      }
    }
  }
  if (lane == 0) {
#pragma unroll
    for (int j = 0; j < 8; j++) ldc[wave][j] = cl[j];
  }
  __syncthreads();
  float* fg = &ws->fAcc[0][0];
  for (int i = tid; i < 2048; i += 256) {
    float ssum = fa[i] + fa[2048 + i] + fa[4096 + i] + fa[6144 + i];
    unsafeAtomicAdd(fg + i, ssum);
  }
  if (tid < 8) {
    unsigned cs = ldc[0][tid] + ldc[1][tid] + ldc[2][tid] + ldc[3][tid];
    if (cs) atomicAdd(&ws->nmk[tid], cs);
  }
}

// ---------------- K5: finalize prototypes ----------------
__global__ __launch_bounds__(512) void k_final(Ws* __restrict__ ws, float* __restrict__ out_protos) {
  int tid = threadIdx.x;
  int r = tid >> 6, lane = tid & 63;
  const float4 f = *(const float4*)(&ws->fAcc[r][lane * 4]);
  float ss = wredf(f.x * f.x + f.y * f.y + f.z * f.z + f.w * f.w);
  float invf = 1.0f / fmaxf(sqrtf(ss), 1e-12f);
  unsigned nr = ws->nmk[r];
  int c = r >> 1;
  unsigned tot = ws->nmk[c * 2] + ws->nmk[c * 2 + 1];
  bool cond = (tot > 0u) && (nr != 0u);
  const float4 p = *(const float4*)(&ws->protoN[r][lane * 4]);
  float u0 = cond ? 0.999f * p.x + 0.001f * (f.x * invf) : p.x;
  float u1 = cond ? 0.999f * p.y + 0.001f * (f.y * invf) : p.y;
  float u2 = cond ? 0.999f * p.z + 0.001f * (f.z * invf) : p.z;
  float u3 = cond ? 0.999f * p.w + 0.001f * (f.w * invf) : p.w;
  float ss2 = wredf(u0 * u0 + u1 * u1 + u2 * u2 + u3 * u3);
  float invn = 1.0f / fmaxf(sqrtf(ss2), 1e-12f);
  float4 o; o.x = u0 * invn; o.y = u1 * invn; o.z = u2 * invn; o.w = u3 * invn;
  *(float4*)(out_protos + r * 256 + lane * 4) = o;
}

// ---------------- launch ----------------
extern "C" void kernel_launch(void* const* d_in, const int* in_sizes, int n_in,
                              void* d_out, int out_size, void* d_ws, size_t ws_size,
                              hipStream_t stream) {
  const float* X = (const float*)d_in[0];
  const int* label = (const int*)d_in[1];
  const float* protos = (const float*)d_in[2];
  const float* fng = (const float*)d_in[3];
  const float* fnb = (const float*)d_in[4];
  const float* mng = (const float*)d_in[5];
  const float* mnb = (const float*)d_in[6];

  float* out = (float*)d_out;
  float* out_nearest = out;                        // 32*4*12544 = 1605632
  float* out_logits = out + 1605632;               // N*8 = 3211264
  float* out_target = out_logits + 3211264;        // N
  float* out_protos = out_target + N_PIX;          // 2048
  Ws* ws = (Ws*)d_ws;

  k_main<<<NBLK, 256, 0, stream>>>(X, label, protos, fng, fnb, mng, mnb, ws, out_nearest, out_logits);
  k_red<<<12, 256, 0, stream>>>(ws);
  k_sink<2><<<512, 256, 0, stream>>>(label, ws);
  k_sink<3><<<512, 256, 0, stream>>>(label, ws);
  k_accum<<<512, 256, 0, stream>>>(X, label, fng, fnb, ws, out_target);
  k_final<<<1, 512, 0, stream>>>(ws, out_protos);
}